// Round 7
// baseline (562.153 us; speedup 1.0000x reference)
//
#include <hip/hip_runtime.h>
#include <hip/hip_bf16.h>
#include <math.h>

#define T_DIM 1024
#define B_DIM 8
#define D_DIM 1024
#define H_DIM 16
#define DH 64
#define M_ROWS 8192          // T*B
#define N_COLS 5120          // 5*D
#define K_DIM 1024
#define PAD 72               // padded bf16 row length (144 B): b128-aligned, conflict-staggered

typedef __attribute__((ext_vector_type(8))) short short8;
typedef __attribute__((ext_vector_type(4))) float floatx4;

static __device__ __forceinline__ unsigned short f2bf(float f){
    unsigned int u = __float_as_uint(f);
    u += 0x7fff + ((u >> 16) & 1);          // RNE
    return (unsigned short)(u >> 16);
}
static __device__ __forceinline__ float sigf(float x){
    return 1.f / (1.f + __expf(-x));
}
static __device__ __forceinline__ float bflo(unsigned int w){ return __uint_as_float(w << 16); }
static __device__ __forceinline__ float bfhi(unsigned int w){ return __uint_as_float(w & 0xffff0000u); }

// DPP butterfly adds on VALU pipe
#define DPPADD(x, ctrl) ((x) + __int_as_float(__builtin_amdgcn_update_dpp(0, __float_as_int(x), (ctrl), 0xF, 0xF, true)))
static __device__ __forceinline__ float red8(float x){
    x = DPPADD(x, 0xB1); x = DPPADD(x, 0x4E); x = DPPADD(x, 0x141); return x;
}
static __device__ __forceinline__ float red16(float x){
    x = red8(x); x = DPPADD(x, 0x140); return x;
}

// ---------------- fp32 -> bf16 conversion ----------------
__global__ void cvt_bf16(const float* __restrict__ src, unsigned short* __restrict__ dst, int n4){
    int i = blockIdx.x*blockDim.x + threadIdx.x;
    int stride = gridDim.x*blockDim.x;
    for (; i < n4; i += stride){
        float4 f = ((const float4*)src)[i];
        ushort4 o;
        o.x = f2bf(f.x); o.y = f2bf(f.y); o.z = f2bf(f.z); o.w = f2bf(f.w);
        ((ushort4*)dst)[i] = o;
    }
}

__global__ void cvt_w(const float* __restrict__ w0, const float* __restrict__ w1,
                      const float* __restrict__ w2, const float* __restrict__ w3,
                      const float* __restrict__ w4, unsigned short* __restrict__ dst){
    int i = blockIdx.x*blockDim.x + threadIdx.x;
    int seg = i >> 18;
    int off = i & 262143;
    const float* src = (seg==0)?w0:(seg==1)?w1:(seg==2)?w2:(seg==3)?w3:w4;
    float4 f = ((const float4*)src)[off];
    ushort4 o;
    o.x = f2bf(f.x); o.y = f2bf(f.y); o.z = f2bf(f.z); o.w = f2bf(f.w);
    ((ushort4*)dst)[i] = o;
}

// ---------------- NT GEMM + lean epilogue ----------------
// KQV record per (bh,t): 512 B = [k bf16 x64 | q bf16 x64 | v fp32 x64]  (k,q RAW)
#define GLD16(g, l) __builtin_amdgcn_global_load_lds(                         \
    (const __attribute__((address_space(1))) void*)(g),                       \
    (__attribute__((address_space(3))) void*)(l), 16, 0, 0)

__global__ __launch_bounds__(256) void gemm_bt(const unsigned short* __restrict__ A,
                                               const unsigned short* __restrict__ B,
                                               unsigned char* __restrict__ KQV,
                                               float* __restrict__ G,
                                               const float* __restrict__ b_alpha,
                                               const float* __restrict__ b_beta){
    __shared__ unsigned short As[128*32];
    __shared__ unsigned short Bs[128*32];
    const int tid = threadIdx.x;
    const int rowBase = blockIdx.y * 128;
    const int colBase = blockIdx.x * 128;
    const int l  = tid & 63;
    const int wv = tid >> 6;
    const int wm = (wv >> 1) * 64;
    const int wn = (wv & 1) * 64;

    floatx4 acc[4][4] = {};

    const int r0 = tid >> 2;
    const int kj = (tid & 3) * 8;
    const unsigned short* gA0 = A + (size_t)(rowBase + r0)      * K_DIM + kj;
    const unsigned short* gA1 = A + (size_t)(rowBase + r0 + 64) * K_DIM + kj;
    const unsigned short* gB0 = B + (size_t)(colBase + r0)      * K_DIM + kj;
    const unsigned short* gB1 = B + (size_t)(colBase + r0 + 64) * K_DIM + kj;
    unsigned short* lA0 = &As[tid*8];
    unsigned short* lA1 = &As[(tid+256)*8];
    unsigned short* lB0 = &Bs[tid*8];
    unsigned short* lB1 = &Bs[(tid+256)*8];

    const int fr = l & 15;
    const int fk = (l >> 4) * 8;

    for (int kc = 0; kc < K_DIM; kc += 32){
        __syncthreads();
        GLD16(gA0 + kc, lA0);
        GLD16(gA1 + kc, lA1);
        GLD16(gB0 + kc, lB0);
        GLD16(gB1 + kc, lB1);
        __syncthreads();
        short8 af[4], bfr[4];
        #pragma unroll
        for (int i = 0; i < 4; i++)
            af[i] = *(const short8*)&As[(wm + i*16 + fr)*32 + fk];
        #pragma unroll
        for (int jj = 0; jj < 4; jj++)
            bfr[jj] = *(const short8*)&Bs[(wn + jj*16 + fr)*32 + fk];
        #pragma unroll
        for (int i = 0; i < 4; i++)
            #pragma unroll
            for (int jj = 0; jj < 4; jj++)
                acc[i][jj] = __builtin_amdgcn_mfma_f32_16x16x32_bf16(af[i], bfr[jj], acc[i][jj], 0, 0, 0);
    }

    const int ntile = blockIdx.x;
    const int l15 = l & 15;
    if (ntile < 24){
        const int gcol = colBase + wn;           // 0..3071
        const int seg  = gcol >> 10;             // 0=q, 1=k, 2=v
        const int h    = (gcol >> 6) & 15;
        const int segOff = (seg == 0) ? 128 : (seg == 1 ? 0 : 256);
        if (seg < 2){
            #pragma unroll
            for (int i = 0; i < 4; i++){
                #pragma unroll
                for (int r = 0; r < 4; r++){
                    const int row = rowBase + wm + i*16 + (l >> 4)*4 + r;
                    const size_t rec = (size_t)((row & 7)*16 + h)*1024 + (row >> 3);
                    unsigned short* rp = (unsigned short*)(KQV + rec*512 + segOff);
                    #pragma unroll
                    for (int jj = 0; jj < 4; jj++)
                        rp[jj*16 + l15] = f2bf(acc[i][jj][r]);
                }
            }
        } else {
            #pragma unroll
            for (int i = 0; i < 4; i++){
                #pragma unroll
                for (int r = 0; r < 4; r++){
                    const int row = rowBase + wm + i*16 + (l >> 4)*4 + r;
                    const size_t rec = (size_t)((row & 7)*16 + h)*1024 + (row >> 3);
                    float* vp = (float*)(KQV + rec*512 + 256);
                    #pragma unroll
                    for (int jj = 0; jj < 4; jj++)
                        vp[jj*16 + l15] = acc[i][jj][r];
                }
            }
        }
    } else {
        const int isBeta = (ntile >= 32) ? 1 : 0;
        const float* bias = isBeta ? b_beta : b_alpha;
        const int gcol0 = colBase + wn - (isBeta ? 4096 : 3072);
        const int hh = gcol0 >> 6;
        float bj[4];
        #pragma unroll
        for (int jj = 0; jj < 4; jj++) bj[jj] = bias[gcol0 + jj*16 + l15];
        #pragma unroll
        for (int i = 0; i < 4; i++){
            #pragma unroll
            for (int r = 0; r < 4; r++){
                float sum = 0.f;
                #pragma unroll
                for (int jj = 0; jj < 4; jj++) sum += sigf(acc[i][jj][r] + bj[jj]);
                sum = red16(sum);
                if (l15 == 0){
                    const int row = rowBase + wm + i*16 + (l >> 4)*4 + r;
                    const int t = row >> 3, bb = row & 7;
                    G[(((size_t)(bb*16 + hh)*1024 + t))*2 + isBeta] = sum * (1.f/64.f);
                }
            }
        }
    }
}

// ---------------- Phase A: per-(bh,chunk) coefficients ----------------
// outputs: Wtg = (I+C)^-1 diag(be) bf16; Ng[t,s] = (r_t/r_s) rq_t rk_s (q_t.k_s), s<=t, bf16;
//          Ktg[e][s] = k_s[e] * r_63 * rk_s / r_s (bf16, prescaled K~^T);
//          rg[t] = float4{r, r*rk, r*rq, 0}
__global__ __launch_bounds__(256) void phasea(const unsigned char* __restrict__ KQV,
                                              const float* __restrict__ G,
                                              unsigned short* __restrict__ Wtg,
                                              unsigned short* __restrict__ Ng,
                                              unsigned short* __restrict__ Ktg,
                                              float4* __restrict__ rg){
    __shared__ unsigned short sKa[64*PAD], sQa[64*PAD];
    __shared__ float sAB[128];
    __shared__ float sKK[4096];
    __shared__ float sX[4096];
    __shared__ float sR[64], sRi[64], sRk[64], sRq[64];

    const int unitIdx = blockIdx.x;
    const int bh = unitIdx >> 4, c = unitIdx & 15;
    const int tid = threadIdx.x;
    const int w = tid>>6, l = tid&63, l15 = l&15, quad = l>>4;
    const unsigned char* gRec = KQV + ((size_t)bh*1024 + c*64)*512;

    #pragma unroll
    for (int it=0; it<2; ++it){
        int flat = it*256 + tid, t = flat>>3, i8 = flat&7;
        float4 kv = *(const float4*)(gRec + t*512 + i8*16);
        float4 qv = *(const float4*)(gRec + t*512 + 128 + i8*16);
        *(float4*)&sKa[t*PAD + i8*8] = kv;
        *(float4*)&sQa[t*PAD + i8*8] = qv;
        // row sumsq (8 bf16 per thread, 8 threads per row)
        unsigned int ku0=__float_as_uint(kv.x), ku1=__float_as_uint(kv.y),
                     ku2=__float_as_uint(kv.z), ku3=__float_as_uint(kv.w);
        unsigned int qu0=__float_as_uint(qv.x), qu1=__float_as_uint(qv.y),
                     qu2=__float_as_uint(qv.z), qu3=__float_as_uint(qv.w);
        float ssk = bflo(ku0)*bflo(ku0)+bfhi(ku0)*bfhi(ku0)+bflo(ku1)*bflo(ku1)+bfhi(ku1)*bfhi(ku1)
                  + bflo(ku2)*bflo(ku2)+bfhi(ku2)*bfhi(ku2)+bflo(ku3)*bflo(ku3)+bfhi(ku3)*bfhi(ku3);
        float ssq = bflo(qu0)*bflo(qu0)+bfhi(qu0)*bfhi(qu0)+bflo(qu1)*bflo(qu1)+bfhi(qu1)*bfhi(qu1)
                  + bflo(qu2)*bflo(qu2)+bfhi(qu2)*bfhi(qu2)+bflo(qu3)*bflo(qu3)+bfhi(qu3)*bfhi(qu3);
        ssk = red8(ssk); ssq = red8(ssq);
        if (i8 == 0){
            sRk[t] = 1.f / fmaxf(sqrtf(ssk), 1e-12f);
            sRq[t] = 1.f / fmaxf(sqrtf(ssq), 1e-12f);
        }
    }
    if (tid < 64){
        float2 ab = *(const float2*)(G + ((size_t)bh*1024 + c*64 + tid)*2);
        sAB[tid*2] = ab.x; sAB[tid*2+1] = ab.y;
    }
    __syncthreads();
    if (tid < 64){
        float p = sAB[tid*2];
        #pragma unroll
        for (int off=1; off<64; off<<=1){
            float y = __shfl_up(p, off);
            if (tid >= off) p *= y;
        }
        sR[tid] = p; sRi[tid] = 1.f/p;
    }
    __syncthreads();

    // KK (waves 0,1) / QK->N (waves 2,3), raw dots scaled by norm/gate factors
    {
        const int isQK = w >> 1;
        const int tmb = (w & 1)*2;
        floatx4 acc[2][4] = {};
        #pragma unroll
        for (int ks=0; ks<2; ++ks){
            short8 aA[2]; short8 bB[4];
            #pragma unroll
            for (int i=0;i<2;++i)
                aA[i] = *(const short8*)&((isQK? sQa : sKa)[((tmb+i)*16 + l15)*PAD + ks*32 + quad*8]);
            #pragma unroll
            for (int j2=0;j2<4;++j2)
                bB[j2] = *(const short8*)&sKa[(j2*16 + l15)*PAD + ks*32 + quad*8];
            #pragma unroll
            for (int i=0;i<2;++i)
                #pragma unroll
                for (int j2=0;j2<4;++j2)
                    acc[i][j2] = __builtin_amdgcn_mfma_f32_16x16x32_bf16(aA[i], bB[j2], acc[i][j2], 0,0,0);
        }
        float frow[2][4];
        #pragma unroll
        for (int i=0;i<2;++i)
            #pragma unroll
            for (int r=0;r<4;++r){
                int t = (tmb+i)*16 + quad*4 + r;
                frow[i][r] = isQK ? (sR[t]*sRq[t]) : (sAB[t*2+1]*sR[t]*sRk[t]);
            }
        #pragma unroll
        for (int j2=0;j2<4;++j2){
            int s = j2*16 + l15;
            float cs = sRi[s]*sRk[s];
            #pragma unroll
            for (int i=0;i<2;++i){
                #pragma unroll
                for (int r=0;r<4;++r){
                    int t = (tmb+i)*16 + quad*4 + r;
                    float v = frow[i][r]*cs*acc[i][j2][r];
                    if (!isQK){
                        sKK[t*64+s] = (s < t) ? v : 0.f;
                    } else {
                        Ng[(size_t)unitIdx*4096 + t*64 + s] = f2bf((s <= t) ? v : 0.f);
                    }
                }
            }
        }
    }

    // prescaled K~^T to global: Ktg[e][s] = k_s[e] * r63 * rk_s / r_s
    {
        const float r63 = sR[63];
        const int s = l;
        const float csl = r63 * sRi[s] * sRk[s];
        #pragma unroll
        for (int m=0; m<16; ++m){
            int e = m*4 + w;
            float kv = __uint_as_float((unsigned)sKa[s*PAD + e] << 16);
            Ktg[(size_t)unitIdx*4096 + e*64 + s] = f2bf(kv * csl);
        }
    }

    #pragma unroll
    for (int e=0; e<16; ++e) sX[tid + e*256] = 0.f;
    __syncthreads();

    // X = (I+C)^-1, column-parallel forward substitution on wave 0
    if (tid < 64){
        const int s = tid;
        if (s == 0) sX[0] = 1.f;
        for (int t=1; t<64; ++t){
            float a0=0.f, a1=0.f;
            int r = 0;
            for (; r+1 < t; r += 2){
                a0 += sKK[t*64+r]   * sX[r*64+s];
                a1 += sKK[t*64+r+1] * sX[(r+1)*64+s];
            }
            if (r < t) a0 += sKK[t*64+r]*sX[r*64+s];
            sX[t*64+s] = (s==t) ? 1.f : -(a0+a1);
        }
    }
    __syncthreads();

    #pragma unroll
    for (int e=0; e<16; ++e){
        int flat = tid + e*256;
        int s = flat&63;
        Wtg[(size_t)unitIdx*4096 + flat] = f2bf(sX[flat]*sAB[s*2+1]);
    }
    if (tid < 64){
        float rt = sR[tid];
        float4 o; o.x = rt; o.y = rt*sRk[tid]; o.z = rt*sRq[tid]; o.w = 0.f;
        rg[(size_t)unitIdx*64 + tid] = o;
    }
}

// ---------------- Phase B: sequential chunk scan via MFMA ----------------
// 512 blocks = (dq*128 + bh); block owns 16 d-rows of S; 2 blocks/CU.
__global__ __launch_bounds__(256) void chunk_scan(const unsigned char* __restrict__ KQV,
                                                  const unsigned short* __restrict__ Wtg,
                                                  const unsigned short* __restrict__ Ng,
                                                  const unsigned short* __restrict__ Ktg,
                                                  const float4* __restrict__ rg,
                                                  const float* __restrict__ S0g,
                                                  float* __restrict__ out){
    __shared__ unsigned short sK[64*PAD], sQ[64*PAD], sWt[64*PAD];
    __shared__ unsigned short sN[2][64*PAD], sKt[2][64*PAD];
    __shared__ unsigned short sUt[16*PAD], sRHS[16*PAD], sS0b[16*PAD];
    __shared__ float4 sr[2][64];

    const int bh = blockIdx.x & 127;
    const int dq = blockIdx.x >> 7;
    const int b = bh >> 4, h = bh & 15;
    const int tid = threadIdx.x;
    const int w = tid >> 6, l = tid & 63, l15 = l & 15, quad = l >> 4;
    const int t0 = w*16 + quad*4;
    const int dBase = dq*16;
    const unsigned char* gRec = KQV + (size_t)bh * (1024*512);
    const size_t outBase = (size_t)b*1024 + h*64 + dBase;

    float4 kst[2], qst[2], wst[2], nst[2], ktst[2];
    float4 rst = {0.f,0.f,0.f,0.f};
    float vCur[4], vNext[4];
    floatx4 Sreg;

    // prologue: chunk 0
    {
        const int unit = bh*16;
        #pragma unroll
        for (int it=0; it<2; ++it){
            int flat = it*256 + tid, t = flat>>3, i8 = flat&7;
            kst[it]  = *(const float4*)(gRec + t*512 +       i8*16);
            qst[it]  = *(const float4*)(gRec + t*512 + 128 + i8*16);
            wst[it]  = *(const float4*)((const unsigned char*)Wtg + (size_t)unit*8192 + (size_t)flat*16);
            nst[it]  = *(const float4*)((const unsigned char*)Ng  + (size_t)unit*8192 + (size_t)flat*16);
            ktst[it] = *(const float4*)((const unsigned char*)Ktg + (size_t)unit*8192 + (size_t)flat*16);
        }
        if (tid < 64) rst = rg[(size_t)unit*64 + tid];
        #pragma unroll
        for (int r=0;r<4;++r)
            vCur[r] = *(const float*)(gRec + (t0+r)*512 + 256 + (dBase + l15)*4);
        #pragma unroll
        for (int r=0;r<4;++r)
            Sreg[r] = S0g[(size_t)bh*4096 + (dBase + quad*4 + r)*64 + w*16 + l15];
        #pragma unroll
        for (int it=0; it<2; ++it){
            int flat = it*256 + tid, t = flat>>3, i8 = flat&7;
            *(float4*)&sK[t*PAD + i8*8]     = kst[it];
            *(float4*)&sQ[t*PAD + i8*8]     = qst[it];
            *(float4*)&sWt[t*PAD + i8*8]    = wst[it];
            *(float4*)&sN[0][t*PAD + i8*8]  = nst[it];
            *(float4*)&sKt[0][t*PAD + i8*8] = ktst[it];
        }
        if (tid < 64) sr[0][tid] = rst;
        #pragma unroll
        for (int r=0;r<4;++r)
            sS0b[(quad*4+r)*PAD + w*16 + l15] = f2bf(Sreg[r]);
    }
    __syncthreads();

    for (int c=0; c<16; ++c){
        const int buf = c & 1;
        if (c < 15){
            const int unit = bh*16 + c + 1;
            const unsigned char* gRecN = gRec + (size_t)(c+1)*64*512;
            #pragma unroll
            for (int it=0; it<2; ++it){
                int flat = it*256 + tid, t = flat>>3, i8 = flat&7;
                kst[it]  = *(const float4*)(gRecN + t*512 +       i8*16);
                qst[it]  = *(const float4*)(gRecN + t*512 + 128 + i8*16);
                wst[it]  = *(const float4*)((const unsigned char*)Wtg + (size_t)unit*8192 + (size_t)flat*16);
                nst[it]  = *(const float4*)((const unsigned char*)Ng  + (size_t)unit*8192 + (size_t)flat*16);
                ktst[it] = *(const float4*)((const unsigned char*)Ktg + (size_t)unit*8192 + (size_t)flat*16);
            }
            if (tid < 64) rst = rg[(size_t)unit*64 + tid];
            #pragma unroll
            for (int r=0;r<4;++r)
                vNext[r] = *(const float*)(gRecN + (t0+r)*512 + 256 + (dBase + l15)*4);
        }

        // stage 1: PT = K*S0^T, OB = Q*S0^T (rows t, cols d in [0,16))
        floatx4 accPT = {}; floatx4 accOB = {};
        #pragma unroll
        for (int ks=0; ks<2; ++ks){
            short8 aK = *(const short8*)&sK[(w*16 + l15)*PAD + ks*32 + quad*8];
            short8 aQ = *(const short8*)&sQ[(w*16 + l15)*PAD + ks*32 + quad*8];
            short8 bS = *(const short8*)&sS0b[l15*PAD + ks*32 + quad*8];
            accPT = __builtin_amdgcn_mfma_f32_16x16x32_bf16(aK, bS, accPT, 0,0,0);
            accOB = __builtin_amdgcn_mfma_f32_16x16x32_bf16(aQ, bS, accOB, 0,0,0);
        }
        float rk4[4], rq4[4];
        #pragma unroll
        for (int r=0;r<4;++r){ float4 g = sr[buf][t0+r]; rk4[r] = g.y; rq4[r] = g.z; }
        {
            uint2 uu;
            uu.x = (unsigned)f2bf(vCur[0] - rk4[0]*accPT[0]) | ((unsigned)f2bf(vCur[1] - rk4[1]*accPT[1])<<16);
            uu.y = (unsigned)f2bf(vCur[2] - rk4[2]*accPT[2]) | ((unsigned)f2bf(vCur[3] - rk4[3]*accPT[3])<<16);
            *(uint2*)&sRHS[l15*PAD + t0] = uu;
        }
        __syncthreads();   // A

        // stage 2: U = Wt * RHS^T
        floatx4 accU = {};
        #pragma unroll
        for (int ks=0; ks<2; ++ks){
            short8 aW = *(const short8*)&sWt[(w*16 + l15)*PAD + ks*32 + quad*8];
            short8 bR = *(const short8*)&sRHS[l15*PAD + ks*32 + quad*8];
            accU = __builtin_amdgcn_mfma_f32_16x16x32_bf16(aW, bR, accU, 0,0,0);
        }
        {
            uint2 uu;
            uu.x = (unsigned)f2bf(accU[0]) | ((unsigned)f2bf(accU[1])<<16);
            uu.y = (unsigned)f2bf(accU[2]) | ((unsigned)f2bf(accU[3])<<16);
            *(uint2*)&sUt[l15*PAD + t0] = uu;
        }
        __syncthreads();   // B

        // stage 3: O = diag(r*rq)*OB + N*U^T ;  S = r63*S0 + U^T * K~^T
        floatx4 accO;
        #pragma unroll
        for (int r=0;r<4;++r) accO[r] = rq4[r]*accOB[r];
        const float rl = sr[buf][63].x;
        floatx4 accS;
        #pragma unroll
        for (int r=0;r<4;++r) accS[r] = rl*Sreg[r];
        #pragma unroll
        for (int ks=0; ks<2; ++ks){
            short8 u8 = *(const short8*)&sUt[l15*PAD + ks*32 + quad*8];
            short8 aN = *(const short8*)&sN[buf][(w*16 + l15)*PAD + ks*32 + quad*8];
            short8 bK = *(const short8*)&sKt[buf][(w*16 + l15)*PAD + ks*32 + quad*8];
            accO = __builtin_amdgcn_mfma_f32_16x16x32_bf16(aN, u8, accO, 0,0,0);
            accS = __builtin_amdgcn_mfma_f32_16x16x32_bf16(u8, bK, accS, 0,0,0);
        }
        Sreg = accS;

        #pragma unroll
        for (int r=0;r<4;++r)
            out[(size_t)(c*64 + t0 + r)*8192 + outBase + l15] = accO[r];
        #pragma unroll
        for (int r=0;r<4;++r)
            sS0b[(quad*4+r)*PAD + w*16 + l15] = f2bf(Sreg[r]);

        if (c < 15){
            #pragma unroll
            for (int it=0; it<2; ++it){
                int flat = it*256 + tid, t = flat>>3, i8 = flat&7;
                *(float4*)&sK[t*PAD + i8*8]          = kst[it];
                *(float4*)&sQ[t*PAD + i8*8]          = qst[it];
                *(float4*)&sWt[t*PAD + i8*8]         = wst[it];
                *(float4*)&sN[buf^1][t*PAD + i8*8]   = nst[it];
                *(float4*)&sKt[buf^1][t*PAD + i8*8]  = ktst[it];
            }
            if (tid < 64) sr[buf^1][tid] = rst;
            #pragma unroll
            for (int r=0;r<4;++r) vCur[r] = vNext[r];
        }
        __syncthreads();   // end of chunk
    }

    // final state
    #pragma unroll
    for (int r=0;r<4;++r)
        out[(size_t)8388608 + (size_t)bh*4096 + (dBase + quad*4 + r)*64 + w*16 + l15] = Sreg[r];
}

extern "C" void kernel_launch(void* const* d_in, const int* in_sizes, int n_in,
                              void* d_out, int out_size, void* d_ws, size_t ws_size,
                              hipStream_t stream){
    const float* x  = (const float*)d_in[0];
    const float* S0 = (const float*)d_in[1];
    const float* Wq = (const float*)d_in[2];
    const float* Wk = (const float*)d_in[3];
    const float* Wv = (const float*)d_in[4];
    const float* Wa = (const float*)d_in[5];
    const float* ba = (const float*)d_in[6];
    const float* Wb = (const float*)d_in[7];
    const float* bb = (const float*)d_in[8];
    float* out = (float*)d_out;

    char* ws = (char*)d_ws;
    unsigned short* Abf = (unsigned short*)ws;                    // 16,777,216
    unsigned short* Bbf = (unsigned short*)(ws + 16777216);       // 10,485,760
    unsigned char*  KQV = (unsigned char*) (ws + 27262976);       // 67,108,864 (128*1024*512)
    float*          G   = (float*)         (ws + 94371840);       //  1,048,576
    unsigned short* Wtg = (unsigned short*)(ws + 95420416);       // 16,777,216 (2048*4096 bf16)
    unsigned short* Ng  = (unsigned short*)(ws + 112197632);      // 16,777,216
    unsigned short* Ktg = (unsigned short*)(ws + 128974848);      // 16,777,216
    float4*         rg  = (float4*)        (ws + 145752064);      //  2,097,152  -> end 147,849,216

    cvt_bf16<<<2048, 256, 0, stream>>>(x, Abf, (M_ROWS*K_DIM)/4);
    cvt_w<<<5120, 256, 0, stream>>>(Wq, Wk, Wv, Wa, Wb, Bbf);

    dim3 gg(N_COLS/128, M_ROWS/128);   // 40 x 64
    gemm_bt<<<gg, 256, 0, stream>>>(Abf, Bbf, KQV, G, ba, bb);

    phasea<<<2048, 256, 0, stream>>>(KQV, G, Wtg, Ng, Ktg, rg);

    chunk_scan<<<512, 256, 0, stream>>>(KQV, Wtg, Ng, Ktg, rg, S0, out);
}